// Round 14
// baseline (75.163 us; speedup 1.0000x reference)
//
#include <hip/hip_runtime.h>
#include <hip/hip_bf16.h>

// Wide_BasicBlock_Q: DoReFa-quantized residual block on MI355X (gfx950).
// Round 13: r12 half-image mega-kernel + halo-row fix.
//   - 512 blocks (image n = blk>>1, rows H0 = (blk&1)*8 .. +7), 1024 thr,
//     LDS 80,768B: slab[19][34][64] i8 + a2p[10][18][128] i8 + asc[8][16][64] bf16
//   - P1: x rows r0..r0+18 -> bn1+actq -> slab; bn_s -> asc
//   - P2: conv1 for a2 rows H0-1..H0+8; the row OUTSIDE the image (a2 row -1
//     for H0=0, a2 row 16 for H0=8) is conv2 zero-padding -> store ZEROS
//     (r12 bug: it ran the bn2+actq epilogue there, actq(bn2(0)) != 0)
//   - P3: conv2 (16 waves, 32co x 32pos) + bf16 shortcut -> fp32 NCHW out
//   - __launch_bounds__(1024,8) pins VGPR<=64 so 2 blocks co-reside

typedef __bf16 bf16x8 __attribute__((ext_vector_type(8)));
typedef float f32x4 __attribute__((ext_vector_type(4)));
typedef int i32x4 __attribute__((ext_vector_type(4)));

#define EPSV 1e-5f

// per-block partial max|w| -> wpart[b] (plain store, deterministic)
__global__ __launch_bounds__(256) void k_wmax(const float* __restrict__ w1,
                                              const float* __restrict__ w2,
                                              float* __restrict__ wpart) {
    int sel = blockIdx.x >> 4;                 // 0: w1, 1: w2
    const float* src = sel ? w2 : w1;
    int cnt = sel ? 128 * 128 * 9 : 128 * 64 * 9;
    float m = 0.f;
    for (int i = (blockIdx.x & 15) * 256 + threadIdx.x; i < cnt; i += 16 * 256)
        m = fmaxf(m, fabsf(src[i]));
#pragma unroll
    for (int off = 32; off > 0; off >>= 1)
        m = fmaxf(m, __shfl_down(m, off));
    __shared__ float red[4];
    if ((threadIdx.x & 63) == 0) red[threadIdx.x >> 6] = m;
    __syncthreads();
    if (threadIdx.x == 0)
        wpart[blockIdx.x] = fmaxf(fmaxf(red[0], red[1]), fmaxf(red[2], red[3]));
}

// bnp layout (floats): [0:64)=sc1 [64:128)=sh1 [128:192)=scs [192:256)=shs
// [256:384)=sc2 [384:512)=sh2 [512]=c1 [513]=c2  (c = 15/(2 tanh(max|w|)))
__global__ void k_bnprep(const float* g1, const float* b1, const float* m1, const float* v1,
                         const float* g2, const float* b2, const float* m2, const float* v2,
                         const float* gs, const float* bs, const float* ms, const float* vs,
                         const float* __restrict__ wpart, float* bnp) {
    int c = threadIdx.x;  // blockDim = 128
    if (c < 64) {
        float s = g1[c] * rsqrtf(v1[c] + EPSV);
        bnp[c] = s;          bnp[64 + c] = b1[c] - m1[c] * s;
        float s2 = gs[c] * rsqrtf(vs[c] + EPSV);
        bnp[128 + c] = s2;   bnp[192 + c] = bs[c] - ms[c] * s2;
    }
    float s = g2[c] * rsqrtf(v2[c] + EPSV);
    bnp[256 + c] = s;        bnp[384 + c] = b2[c] - m2[c] * s;
    if (c < 2) {
        float m = 0.f;
#pragma unroll
        for (int i = 0; i < 16; ++i) m = fmaxf(m, wpart[c * 16 + i]);
        bnp[512 + c] = 15.f / (2.f * tanhf(m));
    }
}

// All weight packs in one dispatch (grid 896):
//  b<288 : w1 -> i8 [(s*128+co)*64+kk], k=s*64+kk, k-order khw*64+ci
//  b<864 : w2 -> i8 same with CIN=128
//  else  : wsw -> bf16 [(s*128+co)*32+kk] (1x1: k=ci), unquantized
__global__ __launch_bounds__(256) void k_wq_all(
        const float* __restrict__ w1, const float* __restrict__ w2,
        const float* __restrict__ wsw,
        signed char* __restrict__ w1qi, signed char* __restrict__ w2qi,
        __bf16* __restrict__ wsq, const float* __restrict__ bnp) {
    int b = blockIdx.x, t = threadIdx.x;
    if (b < 864) {
        bool isw1 = b < 288;
        int idx = (isw1 ? b : b - 288) * 256 + t;
        float c = bnp[512 + (isw1 ? 0 : 1)];
        int kk = idx & 63;
        int co = (idx >> 6) & 127;
        int s = idx >> 13;
        int k = s * 64 + kk;
        int khw, ci;
        const float* src;
        if (isw1) { khw = k >> 6; ci = k & 63;  src = w1 + (co * 64 + ci) * 9 + khw; }
        else      { khw = k >> 7; ci = k & 127; src = w2 + (co * 128 + ci) * 9 + khw; }
        int j = (int)rintf(tanhf(*src) * c + 7.5f);
        (isw1 ? w1qi : w2qi)[idx] = (signed char)(2 * j - 15);
    } else {
        int idx = (b - 864) * 256 + t;
        int kk = idx & 31;
        int co = (idx >> 5) & 127;
        int s = idx >> 12;
        wsq[idx] = (__bf16)wsw[co * 64 + s * 32 + kk];
    }
}

// ---- mega kernel: one half-image per block (512 blocks, 2/CU) ----
__global__ __launch_bounds__(1024, 8) void k_mega(
        const float* __restrict__ x,
        const signed char* __restrict__ w1qi,
        const signed char* __restrict__ w2qi,
        const __bf16* __restrict__ wsq,
        const float* __restrict__ bnp,
        float* __restrict__ out) {
    // LDS: slab 19*34*64 = 41344 | a2p 10*18*128 = 23040 | asc 8*16*64*2 = 16384
    __shared__ __align__(16) char lds_all[41344 + 23040 + 16384];
    signed char* slab = (signed char*)lds_all;
    signed char* a2p  = (signed char*)(lds_all + 41344);
    char*        ascb = lds_all + 41344 + 23040;

    const int t = threadIdx.x;
    const int n = blockIdx.x >> 1;
    const int H0 = (blockIdx.x & 1) * 8;     // out rows H0..H0+7
    const int r0 = H0 ? 13 : 0;              // first staged x row
    const int wv = t >> 6, l = t & 63;
    const int lrow = l & 15, quad = l >> 4;

    // ---- P1a: zero borders (disjoint from interior writes) ----
    if (t < 152) {                           // slab cols 0,33 x 19 rows x 4 chunks
        int ci_ = t >> 2, sub = t & 3;
        int row = ci_ >> 1, col = (ci_ & 1) * 33;
        *(uint4*)(slab + (row * 34 + col) * 64 + sub * 16) = uint4{0u, 0u, 0u, 0u};
    }
    if (t < 160) {                           // a2p cols 0,17 x 10 rows x 8 chunks
        int ci_ = t >> 3, sub = t & 7;
        int row = ci_ >> 1, col = (ci_ & 1) * 17;
        *(uint4*)(a2p + (row * 18 + col) * 128 + sub * 16) = uint4{0u, 0u, 0u, 0u};
    }

    // ---- P1b: x rows r0..r0+18 -> bn1+actq -> slab; bn_s -> asc ----
    // unit u: cq = u/192 (4 channels c0=cq*4), row = (u%192)>>3, w0 = (u&7)*4
#pragma unroll
    for (int it = 0; it < 3; ++it) {
        int u = t + it * 1024;
        int cq = u / 192;
        int rem = u - cq * 192;
        int row = rem >> 3, w0 = (rem & 7) * 4;
        if (row < 19) {
            int hx = r0 + row;
            int c0 = cq * 4;
            float4 s1 = *(const float4*)(bnp + c0);
            float4 h1 = *(const float4*)(bnp + 64 + c0);
            float4 ssv = *(const float4*)(bnp + 128 + c0);
            float4 hsv = *(const float4*)(bnp + 192 + c0);
            const float* s1p = (const float*)&s1;
            const float* h1p = (const float*)&h1;
            const float* ssp = (const float*)&ssv;
            const float* hsp = (const float*)&hsv;
            float4 xr[4];
#pragma unroll
            for (int j = 0; j < 4; ++j)
                xr[j] = *(const float4*)(x + ((size_t)(n * 64 + c0 + j)) * 1024 + hx * 32 + w0);
#pragma unroll
            for (int k = 0; k < 4; ++k) {
                unsigned u32 = 0;
#pragma unroll
                for (int j = 0; j < 4; ++j) {
                    float xv = ((const float*)&xr[j])[k];
                    float v = xv * s1p[j] + h1p[j];
                    int q = (int)rintf(fminf(fmaxf(v, 0.f), 1.f) * 15.f);
                    u32 |= (unsigned)q << (8 * j);
                }
                int pw = w0 + k + 1;
                int cell = row * 34 + pw;
                int key = (pw >> 1) & 3;
                *(unsigned*)(slab + cell * 64 + (((cq >> 2) ^ key) * 16) + (cq & 3) * 4) = u32;
            }
            if (((hx & 1) == 0) && ((unsigned)(hx - 2 * H0) < 16u)) {
                int h2l = (hx >> 1) - H0;    // 0..7
#pragma unroll
                for (int k = 0; k < 4; k += 2) {
                    int w = w0 + k;
                    __bf16 bv[4];
#pragma unroll
                    for (int j = 0; j < 4; ++j) {
                        float xv = ((const float*)&xr[j])[k];
                        bv[j] = (__bf16)(xv * ssp[j] + hsp[j]);
                    }
                    int cell = h2l * 16 + (w >> 1);
                    int key = (w >> 1) & 7;
                    *(uint2*)(ascb + cell * 128 + (((cq >> 1) ^ key) * 16) + (cq & 1) * 8) =
                        *(uint2*)bv;
                }
            }
        }
    }
    __syncthreads();

    // ---- P2: conv1 (3x3 s2 p1) -> a2p rows H0-1..H0+8 (local 0..9) ----
    // 20 assignments: coT = a&1 (64 co), arow = a>>1 (1 a2-row = 16 pos).
    // The assignment whose a2 row lies OUTSIDE the image (row -1 for H0=0,
    // row 16 for H0=8) is conv2 zero-padding: store zeros, skip the conv.
#pragma unroll
    for (int p = 0; p < 2; ++p) {
        int a = wv + p * 16;
        if (a < 20) {
            const int coT = a & 1, arow = a >> 1;
            const bool outside = (H0 == 0) ? (arow == 0) : (arow == 9);
            i32x4 acc1[4] = {};
            if (!outside) {
#pragma unroll
                for (int s = 0; s < 9; ++s) {
                    const int kh = s / 3, kw = s % 3;
                    const int ph = 2 * H0 + 2 * arow + kh - 3;  // absolute x row
                    i32x4 af[4];
#pragma unroll
                    for (int i = 0; i < 4; ++i)
                        af[i] = *(const i32x4*)(w1qi +
                            ((s * 128 + coT * 64 + i * 16 + lrow) * 64 + quad * 16));
                    i32x4 bf = {0, 0, 0, 0};
                    if ((unsigned)ph < 32u) {                   // wave-uniform
                        int sr = ph - r0;
                        int pw = 2 * lrow + kw;
                        int key = (pw >> 1) & 3;
                        bf = *(const i32x4*)(slab + (sr * 34 + pw) * 64 + ((quad ^ key) * 16));
                    }
#pragma unroll
                    for (int i = 0; i < 4; ++i)
                        acc1[i] = __builtin_amdgcn_mfma_i32_16x16x64_i8(af[i], bf, acc1[i], 0, 0, 0);
                }
            }
            // epilogue: bn2+actq -> a2p (zeros for the outside padding row)
#pragma unroll
            for (int i = 0; i < 4; ++i) {
                const int co0 = coT * 64 + i * 16 + quad * 4;
                unsigned u32 = 0;
                if (!outside) {
                    float4 s2 = *(const float4*)(bnp + 256 + co0);
                    float4 h2f = *(const float4*)(bnp + 384 + co0);
                    const float* s2p = (const float*)&s2;
                    const float* h2p = (const float*)&h2f;
#pragma unroll
                    for (int r = 0; r < 4; ++r) {
                        float v = (float)acc1[i][r] * (s2p[r] * (1.f / 225.f)) + h2p[r];
                        int q = (int)rintf(fminf(fmaxf(v, 0.f), 1.f) * 15.f);
                        u32 |= (unsigned)q << (8 * r);
                    }
                }
                int cell = arow * 18 + (lrow + 1);
                int key = (lrow + 1) & 7;
                *(unsigned*)(a2p + cell * 128 + (((co0 >> 4) ^ key) * 16) + (co0 & 15)) = u32;
            }
        }
    }
    __syncthreads();

    // ---- P3: conv2 (3x3 s1 p1, 18 K64-steps) + bf16 shortcut -> out ----
    const int wco = wv & 3, wpos = wv >> 2;  // 4 co-tiles(32) x 4 pos-tiles(2 rows)
    {
        i32x4 acc2[2][2] = {};
#pragma unroll
        for (int s = 0; s < 18; ++s) {
            const int khw = s >> 1, cis = s & 1;
            const int kh = khw / 3, kw = khw % 3;
            i32x4 af[2];
#pragma unroll
            for (int i = 0; i < 2; ++i)
                af[i] = *(const i32x4*)(w2qi +
                    ((s * 128 + wco * 32 + i * 16 + lrow) * 64 + quad * 16));
            i32x4 bf[2];
#pragma unroll
            for (int j = 0; j < 2; ++j) {
                int lr = wpos * 2 + j + kh;              // local a2p row 0..9
                int pw = lrow + kw;                      // padded col 0..17
                int chunk = cis * 4 + quad;
                int key = pw & 7;
                bf[j] = *(const i32x4*)(a2p + (lr * 18 + pw) * 128 + ((chunk ^ key) * 16));
            }
#pragma unroll
            for (int i = 0; i < 2; ++i)
#pragma unroll
                for (int j = 0; j < 2; ++j)
                    acc2[i][j] = __builtin_amdgcn_mfma_i32_16x16x64_i8(af[i], bf[j], acc2[i][j], 0, 0, 0);
        }
        f32x4 accM[2][2];
#pragma unroll
        for (int i = 0; i < 2; ++i)
#pragma unroll
            for (int j = 0; j < 2; ++j)
#pragma unroll
                for (int r = 0; r < 4; ++r)
                    accM[i][j][r] = (float)acc2[i][j][r] * (1.f / 225.f);
        // shortcut: 2 bf16 K32-steps from asc, C-in = accM
#pragma unroll
        for (int s = 0; s < 2; ++s) {
            bf16x8 af[2], bb[2];
#pragma unroll
            for (int i = 0; i < 2; ++i)
                af[i] = *(const bf16x8*)(wsq + (size_t)s * 4096 +
                    ((wco * 32 + i * 16 + lrow) * 32 + quad * 8));
#pragma unroll
            for (int j = 0; j < 2; ++j) {
                int cell = (wpos * 2 + j) * 16 + lrow;
                int sub = s * 4 + quad;
                bb[j] = *(const bf16x8*)(ascb + cell * 128 + ((sub ^ (lrow & 7)) * 16));
            }
#pragma unroll
            for (int i = 0; i < 2; ++i)
#pragma unroll
                for (int j = 0; j < 2; ++j)
                    accM[i][j] = __builtin_amdgcn_mfma_f32_16x16x32_bf16(af[i], bb[j], accM[i][j], 0, 0, 0);
        }
        // store out fp32 NCHW
#pragma unroll
        for (int i = 0; i < 2; ++i) {
            const int co0 = wco * 32 + i * 16 + quad * 4;
#pragma unroll
            for (int j = 0; j < 2; ++j) {
                int pos = (H0 + wpos * 2 + j) * 16 + lrow;
#pragma unroll
                for (int r = 0; r < 4; ++r)
                    out[((size_t)n * 128 + co0 + r) * 256 + pos] = accM[i][j][r];
            }
        }
    }
}

extern "C" void kernel_launch(void* const* d_in, const int* in_sizes, int n_in,
                              void* d_out, int out_size, void* d_ws, size_t ws_size,
                              hipStream_t stream) {
    const float* x   = (const float*)d_in[0];
    const float* w1  = (const float*)d_in[1];
    const float* w2  = (const float*)d_in[2];
    const float* wsw = (const float*)d_in[3];
    const float* g1  = (const float*)d_in[4];
    const float* b1  = (const float*)d_in[5];
    const float* m1  = (const float*)d_in[6];
    const float* v1  = (const float*)d_in[7];
    const float* g2  = (const float*)d_in[8];
    const float* b2  = (const float*)d_in[9];
    const float* m2  = (const float*)d_in[10];
    const float* v2  = (const float*)d_in[11];
    const float* gs  = (const float*)d_in[12];
    const float* bs  = (const float*)d_in[13];
    const float* ms  = (const float*)d_in[14];
    const float* vs  = (const float*)d_in[15];
    float* out = (float*)d_out;
    char* ws = (char*)d_ws;

    // ws layout (bytes), ~256 KB total
    signed char* w1qi = (signed char*)(ws);                 // 73,728 i8
    signed char* w2qi = (signed char*)(ws + 73728);         // 147,456 i8
    __bf16*      wsq  = (__bf16*)(ws + 221184);             // 8,192 bf16
    float*       bnp  = (float*)(ws + 237568);              // 514 floats
    float*       wprt = (float*)(ws + 240128);              // 32 floats

    k_wmax<<<32, 256, 0, stream>>>(w1, w2, wprt);
    k_bnprep<<<1, 128, 0, stream>>>(g1, b1, m1, v1, g2, b2, m2, v2,
                                    gs, bs, ms, vs, wprt, bnp);
    k_wq_all<<<896, 256, 0, stream>>>(w1, w2, wsw, w1qi, w2qi, wsq, bnp);
    k_mega<<<512, 1024, 0, stream>>>(x, w1qi, w2qi, wsq, bnp, out);
}

// Round 15
// 72.080 us; speedup vs baseline: 1.0428x; 1.0428x over previous
//
#include <hip/hip_runtime.h>
#include <hip/hip_bf16.h>

// Wide_BasicBlock_Q: DoReFa-quantized residual block on MI355X (gfx950).
// Round 14: r13 half-image mega-kernel, spill fix.
//   - r13 post-mortem: (1024,8) caps VGPR at 64; fully-unrolled P2/P3 K-loops
//     hoisted all weight loads -> ~22MB scratch spill (WRITE 55MB), 70µs.
//   - Fix: #pragma unroll 1 on P2/P3 K-loops (no hoisting, per-step pressure
//     ~50 VGPR); latency covered by TLP (2 blocks/CU = 8 waves/SIMD).
//   - kh,kw from runtime step via (k*11)>>5 magic (k<9), no divides.

typedef __bf16 bf16x8 __attribute__((ext_vector_type(8)));
typedef float f32x4 __attribute__((ext_vector_type(4)));
typedef int i32x4 __attribute__((ext_vector_type(4)));

#define EPSV 1e-5f

// per-block partial max|w| -> wpart[b] (plain store, deterministic)
__global__ __launch_bounds__(256) void k_wmax(const float* __restrict__ w1,
                                              const float* __restrict__ w2,
                                              float* __restrict__ wpart) {
    int sel = blockIdx.x >> 4;                 // 0: w1, 1: w2
    const float* src = sel ? w2 : w1;
    int cnt = sel ? 128 * 128 * 9 : 128 * 64 * 9;
    float m = 0.f;
    for (int i = (blockIdx.x & 15) * 256 + threadIdx.x; i < cnt; i += 16 * 256)
        m = fmaxf(m, fabsf(src[i]));
#pragma unroll
    for (int off = 32; off > 0; off >>= 1)
        m = fmaxf(m, __shfl_down(m, off));
    __shared__ float red[4];
    if ((threadIdx.x & 63) == 0) red[threadIdx.x >> 6] = m;
    __syncthreads();
    if (threadIdx.x == 0)
        wpart[blockIdx.x] = fmaxf(fmaxf(red[0], red[1]), fmaxf(red[2], red[3]));
}

// bnp layout (floats): [0:64)=sc1 [64:128)=sh1 [128:192)=scs [192:256)=shs
// [256:384)=sc2 [384:512)=sh2 [512]=c1 [513]=c2  (c = 15/(2 tanh(max|w|)))
__global__ void k_bnprep(const float* g1, const float* b1, const float* m1, const float* v1,
                         const float* g2, const float* b2, const float* m2, const float* v2,
                         const float* gs, const float* bs, const float* ms, const float* vs,
                         const float* __restrict__ wpart, float* bnp) {
    int c = threadIdx.x;  // blockDim = 128
    if (c < 64) {
        float s = g1[c] * rsqrtf(v1[c] + EPSV);
        bnp[c] = s;          bnp[64 + c] = b1[c] - m1[c] * s;
        float s2 = gs[c] * rsqrtf(vs[c] + EPSV);
        bnp[128 + c] = s2;   bnp[192 + c] = bs[c] - ms[c] * s2;
    }
    float s = g2[c] * rsqrtf(v2[c] + EPSV);
    bnp[256 + c] = s;        bnp[384 + c] = b2[c] - m2[c] * s;
    if (c < 2) {
        float m = 0.f;
#pragma unroll
        for (int i = 0; i < 16; ++i) m = fmaxf(m, wpart[c * 16 + i]);
        bnp[512 + c] = 15.f / (2.f * tanhf(m));
    }
}

// All weight packs in one dispatch (grid 896):
//  b<288 : w1 -> i8 [(s*128+co)*64+kk], k=s*64+kk, k-order khw*64+ci
//  b<864 : w2 -> i8 same with CIN=128
//  else  : wsw -> bf16 [(s*128+co)*32+kk] (1x1: k=ci), unquantized
__global__ __launch_bounds__(256) void k_wq_all(
        const float* __restrict__ w1, const float* __restrict__ w2,
        const float* __restrict__ wsw,
        signed char* __restrict__ w1qi, signed char* __restrict__ w2qi,
        __bf16* __restrict__ wsq, const float* __restrict__ bnp) {
    int b = blockIdx.x, t = threadIdx.x;
    if (b < 864) {
        bool isw1 = b < 288;
        int idx = (isw1 ? b : b - 288) * 256 + t;
        float c = bnp[512 + (isw1 ? 0 : 1)];
        int kk = idx & 63;
        int co = (idx >> 6) & 127;
        int s = idx >> 13;
        int k = s * 64 + kk;
        int khw, ci;
        const float* src;
        if (isw1) { khw = k >> 6; ci = k & 63;  src = w1 + (co * 64 + ci) * 9 + khw; }
        else      { khw = k >> 7; ci = k & 127; src = w2 + (co * 128 + ci) * 9 + khw; }
        int j = (int)rintf(tanhf(*src) * c + 7.5f);
        (isw1 ? w1qi : w2qi)[idx] = (signed char)(2 * j - 15);
    } else {
        int idx = (b - 864) * 256 + t;
        int kk = idx & 31;
        int co = (idx >> 5) & 127;
        int s = idx >> 12;
        wsq[idx] = (__bf16)wsw[co * 64 + s * 32 + kk];
    }
}

// ---- mega kernel: one half-image per block (512 blocks, 2/CU) ----
__global__ __launch_bounds__(1024, 8) void k_mega(
        const float* __restrict__ x,
        const signed char* __restrict__ w1qi,
        const signed char* __restrict__ w2qi,
        const __bf16* __restrict__ wsq,
        const float* __restrict__ bnp,
        float* __restrict__ out) {
    // LDS: slab 19*34*64 = 41344 | a2p 10*18*128 = 23040 | asc 8*16*64*2 = 16384
    __shared__ __align__(16) char lds_all[41344 + 23040 + 16384];
    signed char* slab = (signed char*)lds_all;
    signed char* a2p  = (signed char*)(lds_all + 41344);
    char*        ascb = lds_all + 41344 + 23040;

    const int t = threadIdx.x;
    const int n = blockIdx.x >> 1;
    const int H0 = (blockIdx.x & 1) * 8;     // out rows H0..H0+7
    const int r0 = H0 ? 13 : 0;              // first staged x row
    const int wv = t >> 6, l = t & 63;
    const int lrow = l & 15, quad = l >> 4;

    // ---- P1a: zero borders (disjoint from interior writes) ----
    if (t < 152) {                           // slab cols 0,33 x 19 rows x 4 chunks
        int ci_ = t >> 2, sub = t & 3;
        int row = ci_ >> 1, col = (ci_ & 1) * 33;
        *(uint4*)(slab + (row * 34 + col) * 64 + sub * 16) = uint4{0u, 0u, 0u, 0u};
    }
    if (t < 160) {                           // a2p cols 0,17 x 10 rows x 8 chunks
        int ci_ = t >> 3, sub = t & 7;
        int row = ci_ >> 1, col = (ci_ & 1) * 17;
        *(uint4*)(a2p + (row * 18 + col) * 128 + sub * 16) = uint4{0u, 0u, 0u, 0u};
    }

    // ---- P1b: x rows r0..r0+18 -> bn1+actq -> slab; bn_s -> asc ----
    // unit u: cq = u/192 (4 channels c0=cq*4), row = (u%192)>>3, w0 = (u&7)*4
#pragma unroll
    for (int it = 0; it < 3; ++it) {
        int u = t + it * 1024;
        int cq = u / 192;
        int rem = u - cq * 192;
        int row = rem >> 3, w0 = (rem & 7) * 4;
        if (row < 19) {
            int hx = r0 + row;
            int c0 = cq * 4;
            float4 s1 = *(const float4*)(bnp + c0);
            float4 h1 = *(const float4*)(bnp + 64 + c0);
            float4 ssv = *(const float4*)(bnp + 128 + c0);
            float4 hsv = *(const float4*)(bnp + 192 + c0);
            const float* s1p = (const float*)&s1;
            const float* h1p = (const float*)&h1;
            const float* ssp = (const float*)&ssv;
            const float* hsp = (const float*)&hsv;
            float4 xr[4];
#pragma unroll
            for (int j = 0; j < 4; ++j)
                xr[j] = *(const float4*)(x + ((size_t)(n * 64 + c0 + j)) * 1024 + hx * 32 + w0);
#pragma unroll
            for (int k = 0; k < 4; ++k) {
                unsigned u32 = 0;
#pragma unroll
                for (int j = 0; j < 4; ++j) {
                    float xv = ((const float*)&xr[j])[k];
                    float v = xv * s1p[j] + h1p[j];
                    int q = (int)rintf(fminf(fmaxf(v, 0.f), 1.f) * 15.f);
                    u32 |= (unsigned)q << (8 * j);
                }
                int pw = w0 + k + 1;
                int cell = row * 34 + pw;
                int key = (pw >> 1) & 3;
                *(unsigned*)(slab + cell * 64 + (((cq >> 2) ^ key) * 16) + (cq & 3) * 4) = u32;
            }
            if (((hx & 1) == 0) && ((unsigned)(hx - 2 * H0) < 16u)) {
                int h2l = (hx >> 1) - H0;    // 0..7
#pragma unroll
                for (int k = 0; k < 4; k += 2) {
                    int w = w0 + k;
                    __bf16 bv[4];
#pragma unroll
                    for (int j = 0; j < 4; ++j) {
                        float xv = ((const float*)&xr[j])[k];
                        bv[j] = (__bf16)(xv * ssp[j] + hsp[j]);
                    }
                    int cell = h2l * 16 + (w >> 1);
                    int key = (w >> 1) & 7;
                    *(uint2*)(ascb + cell * 128 + (((cq >> 1) ^ key) * 16) + (cq & 1) * 8) =
                        *(uint2*)bv;
                }
            }
        }
    }
    __syncthreads();

    // ---- P2: conv1 (3x3 s2 p1) -> a2p rows H0-1..H0+8 (local 0..9) ----
    // 20 assignments: coT = a&1 (64 co), arow = a>>1 (1 a2-row = 16 pos).
    // The assignment whose a2 row lies OUTSIDE the image (row -1 for H0=0,
    // row 16 for H0=8) is conv2 zero-padding: store zeros, skip the conv.
#pragma unroll
    for (int p = 0; p < 2; ++p) {
        int a = wv + p * 16;
        if (a < 20) {
            const int coT = a & 1, arow = a >> 1;
            const bool outside = (H0 == 0) ? (arow == 0) : (arow == 9);
            i32x4 acc1[4] = {};
            if (!outside) {
#pragma unroll 1                      // NO full unroll: pressure cap (spill fix)
                for (int s = 0; s < 9; ++s) {
                    const int kh = (s * 11) >> 5;               // s/3, s<9
                    const int kw = s - 3 * kh;
                    const int ph = 2 * H0 + 2 * arow + kh - 3;  // absolute x row
                    i32x4 af[4];
#pragma unroll
                    for (int i = 0; i < 4; ++i)
                        af[i] = *(const i32x4*)(w1qi +
                            ((s * 128 + coT * 64 + i * 16 + lrow) * 64 + quad * 16));
                    i32x4 bf = {0, 0, 0, 0};
                    if ((unsigned)ph < 32u) {                   // wave-uniform
                        int sr = ph - r0;
                        int pw = 2 * lrow + kw;
                        int key = (pw >> 1) & 3;
                        bf = *(const i32x4*)(slab + (sr * 34 + pw) * 64 + ((quad ^ key) * 16));
                    }
#pragma unroll
                    for (int i = 0; i < 4; ++i)
                        acc1[i] = __builtin_amdgcn_mfma_i32_16x16x64_i8(af[i], bf, acc1[i], 0, 0, 0);
                }
            }
            // epilogue: bn2+actq -> a2p (zeros for the outside padding row)
#pragma unroll
            for (int i = 0; i < 4; ++i) {
                const int co0 = coT * 64 + i * 16 + quad * 4;
                unsigned u32 = 0;
                if (!outside) {
                    float4 s2 = *(const float4*)(bnp + 256 + co0);
                    float4 h2f = *(const float4*)(bnp + 384 + co0);
                    const float* s2p = (const float*)&s2;
                    const float* h2p = (const float*)&h2f;
#pragma unroll
                    for (int r = 0; r < 4; ++r) {
                        float v = (float)acc1[i][r] * (s2p[r] * (1.f / 225.f)) + h2p[r];
                        int q = (int)rintf(fminf(fmaxf(v, 0.f), 1.f) * 15.f);
                        u32 |= (unsigned)q << (8 * r);
                    }
                }
                int cell = arow * 18 + (lrow + 1);
                int key = (lrow + 1) & 7;
                *(unsigned*)(a2p + cell * 128 + (((co0 >> 4) ^ key) * 16) + (co0 & 15)) = u32;
            }
        }
    }
    __syncthreads();

    // ---- P3: conv2 (3x3 s1 p1, 18 K64-steps) + bf16 shortcut -> out ----
    const int wco = wv & 3, wpos = wv >> 2;  // 4 co-tiles(32) x 4 pos-tiles(2 rows)
    {
        i32x4 acc2[2][2] = {};
#pragma unroll 1                      // NO full unroll: pressure cap (spill fix)
        for (int s = 0; s < 18; ++s) {
            const int khw = s >> 1, cis = s & 1;
            const int kh = (khw * 11) >> 5;              // khw/3, khw<9
            const int kw = khw - 3 * kh;
            i32x4 af[2];
#pragma unroll
            for (int i = 0; i < 2; ++i)
                af[i] = *(const i32x4*)(w2qi +
                    ((s * 128 + wco * 32 + i * 16 + lrow) * 64 + quad * 16));
            i32x4 bf[2];
#pragma unroll
            for (int j = 0; j < 2; ++j) {
                int lr = wpos * 2 + j + kh;              // local a2p row 0..9
                int pw = lrow + kw;                      // padded col 0..17
                int chunk = cis * 4 + quad;
                int key = pw & 7;
                bf[j] = *(const i32x4*)(a2p + (lr * 18 + pw) * 128 + ((chunk ^ key) * 16));
            }
#pragma unroll
            for (int i = 0; i < 2; ++i)
#pragma unroll
                for (int j = 0; j < 2; ++j)
                    acc2[i][j] = __builtin_amdgcn_mfma_i32_16x16x64_i8(af[i], bf[j], acc2[i][j], 0, 0, 0);
        }
        f32x4 accM[2][2];
#pragma unroll
        for (int i = 0; i < 2; ++i)
#pragma unroll
            for (int j = 0; j < 2; ++j)
#pragma unroll
                for (int r = 0; r < 4; ++r)
                    accM[i][j][r] = (float)acc2[i][j][r] * (1.f / 225.f);
        // shortcut: 2 bf16 K32-steps from asc, C-in = accM
#pragma unroll
        for (int s = 0; s < 2; ++s) {
            bf16x8 af[2], bb[2];
#pragma unroll
            for (int i = 0; i < 2; ++i)
                af[i] = *(const bf16x8*)(wsq + (size_t)s * 4096 +
                    ((wco * 32 + i * 16 + lrow) * 32 + quad * 8));
#pragma unroll
            for (int j = 0; j < 2; ++j) {
                int cell = (wpos * 2 + j) * 16 + lrow;
                int sub = s * 4 + quad;
                bb[j] = *(const bf16x8*)(ascb + cell * 128 + ((sub ^ (lrow & 7)) * 16));
            }
#pragma unroll
            for (int i = 0; i < 2; ++i)
#pragma unroll
                for (int j = 0; j < 2; ++j)
                    accM[i][j] = __builtin_amdgcn_mfma_f32_16x16x32_bf16(af[i], bb[j], accM[i][j], 0, 0, 0);
        }
        // store out fp32 NCHW
#pragma unroll
        for (int i = 0; i < 2; ++i) {
            const int co0 = wco * 32 + i * 16 + quad * 4;
#pragma unroll
            for (int j = 0; j < 2; ++j) {
                int pos = (H0 + wpos * 2 + j) * 16 + lrow;
#pragma unroll
                for (int r = 0; r < 4; ++r)
                    out[((size_t)n * 128 + co0 + r) * 256 + pos] = accM[i][j][r];
            }
        }
    }
}

extern "C" void kernel_launch(void* const* d_in, const int* in_sizes, int n_in,
                              void* d_out, int out_size, void* d_ws, size_t ws_size,
                              hipStream_t stream) {
    const float* x   = (const float*)d_in[0];
    const float* w1  = (const float*)d_in[1];
    const float* w2  = (const float*)d_in[2];
    const float* wsw = (const float*)d_in[3];
    const float* g1  = (const float*)d_in[4];
    const float* b1  = (const float*)d_in[5];
    const float* m1  = (const float*)d_in[6];
    const float* v1  = (const float*)d_in[7];
    const float* g2  = (const float*)d_in[8];
    const float* b2  = (const float*)d_in[9];
    const float* m2  = (const float*)d_in[10];
    const float* v2  = (const float*)d_in[11];
    const float* gs  = (const float*)d_in[12];
    const float* bs  = (const float*)d_in[13];
    const float* ms  = (const float*)d_in[14];
    const float* vs  = (const float*)d_in[15];
    float* out = (float*)d_out;
    char* ws = (char*)d_ws;

    // ws layout (bytes), ~256 KB total
    signed char* w1qi = (signed char*)(ws);                 // 73,728 i8
    signed char* w2qi = (signed char*)(ws + 73728);         // 147,456 i8
    __bf16*      wsq  = (__bf16*)(ws + 221184);             // 8,192 bf16
    float*       bnp  = (float*)(ws + 237568);              // 514 floats
    float*       wprt = (float*)(ws + 240128);              // 32 floats

    k_wmax<<<32, 256, 0, stream>>>(w1, w2, wprt);
    k_bnprep<<<1, 128, 0, stream>>>(g1, b1, m1, v1, g2, b2, m2, v2,
                                    gs, bs, ms, vs, wprt, bnp);
    k_wq_all<<<896, 256, 0, stream>>>(w1, w2, wsw, w1qi, w2qi, wsq, bnp);
    k_mega<<<512, 1024, 0, stream>>>(x, w1qi, w2qi, wsq, bnp, out);
}